// Round 5
// baseline (225.053 us; speedup 1.0000x reference)
//
#include <hip/hip_runtime.h>

// KNRM forward, MI355X (gfx950). R4.
// R3 post-mortem: no-spill didn't help (188us) -> latency-bound: 10 barrier-
// separated staging phases/block expose the full gather latency; <=2 resident
// blocks/CU can't hide it. R4: (a) T14 async-STAGE split -- global loads for
// chunk c+1 issued before computing chunk c (32 prefetch VGPRs), LDS write after
// the post-compute barrier; (b) waves_per_eu(3,3): reg budget ~170 (no spill,
// unlike the 4-wave/128 point) with 3 blocks/CU residency (vs 2).

typedef __attribute__((ext_vector_type(8))) short bf16x8;
typedef __attribute__((ext_vector_type(4))) float f32x4;

__device__ __forceinline__ unsigned short f2bf(float f) {   // RNE float->bf16
    unsigned u = __float_as_uint(f);
    u += 0x7fffu + ((u >> 16) & 1u);
    return (unsigned short)(u >> 16);
}
__device__ __forceinline__ float bf2f(unsigned short h) {
    return __uint_as_float(((unsigned)h) << 16);
}

// Issue the 8 gather loads for 64 rows (one float4 per thread per row-group).
__device__ __forceinline__ void stage_load(const float* __restrict__ emb,
                                           const int* __restrict__ ids,
                                           float4 (&v)[8], int tid)
{
    const int lg = tid >> 5;   // row group 0..7
    const int ln = tid & 31;   // lane within row
    #pragma unroll
    for (int i = 0; i < 8; i++) {
        const int id = ids[i * 8 + lg];
        v[i] = *reinterpret_cast<const float4*>(emb + (size_t)id * 128 + ln * 4);
    }
}

// Normalize, split to bf16 hi/lo, store swizzled (16B-chunk (k>>3)^(r&15); 0 conflicts).
__device__ __forceinline__ void stage_write(const float4 (&v)[8],
                                            unsigned short* __restrict__ hi,
                                            unsigned short* __restrict__ lo,
                                            int tid)
{
    const int lg = tid >> 5;
    const int ln = tid & 31;
    #pragma unroll
    for (int i = 0; i < 8; i++) {
        const int row = i * 8 + lg;
        float ss = v[i].x*v[i].x + v[i].y*v[i].y + v[i].z*v[i].z + v[i].w*v[i].w;
        #pragma unroll
        for (int m = 16; m >= 1; m >>= 1) ss += __shfl_xor(ss, m);   // 32-lane row reduce
        const float rn = 1.0f / (sqrtf(ss) + 1e-13f);                // reference eps
        const float f0 = v[i].x*rn, f1 = v[i].y*rn, f2 = v[i].z*rn, f3 = v[i].w*rn;
        const unsigned short h0 = f2bf(f0), h1 = f2bf(f1), h2 = f2bf(f2), h3 = f2bf(f3);
        const unsigned short g0 = f2bf(f0 - bf2f(h0)), g1 = f2bf(f1 - bf2f(h1));
        const unsigned short g2 = f2bf(f2 - bf2f(h2)), g3 = f2bf(f3 - bf2f(h3));
        const int off = row*128 + (((ln >> 1) ^ (row & 15)) << 3) + ((ln & 1) << 2);
        *reinterpret_cast<uint2*>(hi + off) =
            make_uint2((unsigned)h0 | ((unsigned)h1 << 16), (unsigned)h2 | ((unsigned)h3 << 16));
        *reinterpret_cast<uint2*>(lo + off) =
            make_uint2((unsigned)g0 | ((unsigned)g1 << 16), (unsigned)g2 | ((unsigned)g3 << 16));
    }
}

// 21 kernel contributions of one matching value m; sp[i] accumulates true k_i.
// Geometric ladder: k_{10+j} = t0*R^j*e^{-j(j+1)/2}, k_{10-j} = t0*R^-j*e^{-j(j-1)/2}.
__device__ __forceinline__ void apply_el(float m, float (&sp)[21]) {
    const float dm = m - 0.05f;
    const float x  = m * 14.426950408889634f;                                // 10*log2(e)*m
    const float t0 = __builtin_amdgcn_exp2f(dm * dm * -72.13475204444817f);  // k_10
    const float R  = __builtin_amdgcn_exp2f(x);                              // e^{10m}
    const float Ri = __builtin_amdgcn_exp2f(-x);                             // e^{-10m}
    sp[10] += t0;
    float tu = t0;
    tu *= R;  sp[11] = fmaf(tu, 3.6787944117e-1f,  sp[11]);  // e^-1
    tu *= R;  sp[12] = fmaf(tu, 4.9787068368e-2f,  sp[12]);  // e^-3
    tu *= R;  sp[13] = fmaf(tu, 2.4787521767e-3f,  sp[13]);  // e^-6
    tu *= R;  sp[14] = fmaf(tu, 4.5399929762e-5f,  sp[14]);  // e^-10
    tu *= R;  sp[15] = fmaf(tu, 3.0590232050e-7f,  sp[15]);  // e^-15
    tu *= R;  sp[16] = fmaf(tu, 7.5825604279e-10f, sp[16]);  // e^-21
    tu *= R;  sp[17] = fmaf(tu, 6.9144001069e-13f, sp[17]);  // e^-28
    tu *= R;  sp[18] = fmaf(tu, 2.3195228302e-16f, sp[18]);  // e^-36
    tu *= R;  sp[19] = fmaf(tu, 2.8625185805e-20f, sp[19]);  // e^-45
    float td = t0;
    td *= Ri; sp[9] += td;                                   // e^0
    td *= Ri; sp[8] = fmaf(td, 3.6787944117e-1f,  sp[8]);    // e^-1
    td *= Ri; sp[7] = fmaf(td, 4.9787068368e-2f,  sp[7]);    // e^-3
    td *= Ri; sp[6] = fmaf(td, 2.4787521767e-3f,  sp[6]);    // e^-6
    td *= Ri; sp[5] = fmaf(td, 4.5399929762e-5f,  sp[5]);    // e^-10
    td *= Ri; sp[4] = fmaf(td, 3.0590232050e-7f,  sp[4]);    // e^-15
    td *= Ri; sp[3] = fmaf(td, 7.5825604279e-10f, sp[3]);    // e^-21
    td *= Ri; sp[2] = fmaf(td, 6.9144001069e-13f, sp[2]);    // e^-28
    td *= Ri; sp[1] = fmaf(td, 2.3195228302e-16f, sp[1]);    // e^-36
    td *= Ri; sp[0] = fmaf(td, 2.8625185805e-20f, sp[0]);    // e^-45
    const float e = m - 1.0f;                                // exact-match (sigma=1e-3)
    sp[20] += __builtin_amdgcn_exp2f(e * e * -721347.5204444817f);
}

__global__ __launch_bounds__(256) __attribute__((amdgpu_waves_per_eu(3, 3)))
void knrm_kernel(const int* __restrict__ q1, const int* __restrict__ d1,
                 const int* __restrict__ q2, const int* __restrict__ d2,
                 const float* __restrict__ emb,
                 const float* __restrict__ W1, const float* __restrict__ b1,
                 const float* __restrict__ W2, const float* __restrict__ b2,
                 const float* __restrict__ W3, const float* __restrict__ b3,
                 float* __restrict__ out)
{
    __shared__ unsigned short sh_h[64*128], sh_l[64*128];   // 16KB each; q then d chunks
    __shared__ float S[64][21];
    __shared__ float KMs[2][21];
    __shared__ float x1s[2][10], x2s[2][5];

    const int tid = threadIdx.x;
    const int bb  = blockIdx.x;
    const int w   = tid >> 6;     // wave 0..3 -> q rows 16w..16w+15
    const int l   = tid & 63;
    const int lr  = l & 15;       // MFMA row-in-tile (A) / col=q (B,C)
    const int lh  = l >> 4;       // k-group

    float4 v[8];                  // staging prefetch (32 VGPR)
    stage_load(emb, q1 + bb * 64, v, tid);      // q1 in flight

    for (int p = 0; p < 2; p++) {
        const int* dids = (p == 0 ? d1 : d2) + bb * 256;

        stage_write(v, sh_h, sh_l, tid);        // q staged (p=1: sh free since c=3 barrier)
        stage_load(emb, dids, v, tid);          // d chunk 0 in flight
        __syncthreads();                        // q visible

        // Hoist B (q-side) fragments to registers for the whole pass (32 VGPR).
        bf16x8 Bh[4], Bl[4];
        const int qrow = w * 16 + lr;
        #pragma unroll
        for (int ks = 0; ks < 4; ks++) {
            const int off = qrow*128 + (((ks*4 + lh) ^ (qrow & 15)) << 3);
            Bh[ks] = *reinterpret_cast<const bf16x8*>(sh_h + off);
            Bl[ks] = *reinterpret_cast<const bf16x8*>(sh_l + off);
        }
        __syncthreads();                        // B reads done, sh free
        stage_write(v, sh_h, sh_l, tid);        // d chunk 0
        stage_load(emb, dids + 64, v, tid);     // d chunk 1 in flight
        __syncthreads();                        // chunk 0 visible

        float sp[21];
        #pragma unroll
        for (int i = 0; i < 21; i++) sp[i] = 0.0f;

        for (int c = 0; c < 4; c++) {
            #pragma unroll
            for (int dt = 0; dt < 4; dt += 2) {              // 2 interleaved MFMA chains
                f32x4 C0 = {0.f,0.f,0.f,0.f}, C1 = {0.f,0.f,0.f,0.f};
                #pragma unroll
                for (int ks = 0; ks < 4; ks++) {
                    const int r0 = dt*16 + lr;
                    const int r1 = (dt+1)*16 + lr;
                    const int o0 = r0*128 + (((ks*4 + lh) ^ (r0 & 15)) << 3);
                    const int o1 = r1*128 + (((ks*4 + lh) ^ (r1 & 15)) << 3);
                    const bf16x8 A0h = *reinterpret_cast<const bf16x8*>(sh_h + o0);
                    const bf16x8 A0l = *reinterpret_cast<const bf16x8*>(sh_l + o0);
                    const bf16x8 A1h = *reinterpret_cast<const bf16x8*>(sh_h + o1);
                    const bf16x8 A1l = *reinterpret_cast<const bf16x8*>(sh_l + o1);
                    C0 = __builtin_amdgcn_mfma_f32_16x16x32_bf16(A0h, Bh[ks], C0, 0, 0, 0);
                    C1 = __builtin_amdgcn_mfma_f32_16x16x32_bf16(A1h, Bh[ks], C1, 0, 0, 0);
                    C0 = __builtin_amdgcn_mfma_f32_16x16x32_bf16(A0h, Bl[ks], C0, 0, 0, 0);
                    C1 = __builtin_amdgcn_mfma_f32_16x16x32_bf16(A1h, Bl[ks], C1, 0, 0, 0);
                    C0 = __builtin_amdgcn_mfma_f32_16x16x32_bf16(A0l, Bh[ks], C0, 0, 0, 0);
                    C1 = __builtin_amdgcn_mfma_f32_16x16x32_bf16(A1l, Bh[ks], C1, 0, 0, 0);
                }
                #pragma unroll
                for (int r = 0; r < 4; r++) { apply_el(C0[r], sp); apply_el(C1[r], sp); }
            }
            __syncthreads();                                 // chunk c reads done
            if (c < 3) {
                stage_write(v, sh_h, sh_l, tid);             // chunk c+1
                if (c < 2)       stage_load(emb, dids + (c + 2) * 64, v, tid);  // chunk c+2
                else if (p == 0) stage_load(emb, q2 + bb * 64, v, tid);         // next pass's q
                __syncthreads();                             // chunk c+1 visible
            }
        }

        // Reduce sp over the 4 lanes sharing a q column (sp holds true k sums).
        #pragma unroll
        for (int i = 0; i < 21; i++) {
            float t = sp[i];
            t += __shfl_xor(t, 16);
            t += __shfl_xor(t, 32);
            sp[i] = t;
        }
        if (l < 16) {
            #pragma unroll
            for (int i = 0; i < 21; i++) S[w*16 + l][i] = sp[i];
        }
        __syncthreads();   // S visible

        if (tid < 64) {    // wave 0: KM_i = sum_q log1p(S[q][i])
            #pragma unroll
            for (int i = 0; i < 21; i++) {
                float t = log1pf(S[tid][i]);
                #pragma unroll
                for (int m = 1; m <= 32; m <<= 1) t += __shfl_xor(t, m);
                if (tid == 0) KMs[p][i] = t;
            }
        }
        // no barrier needed here: p=1 staging touches sh_*, not S/KMs; later barriers order KMs for MLP
    }

    // tiny MLP (relu before each linear) + sigmoid(l1 - l2)
    __syncthreads();
    if (tid < 10) {
        for (int p = 0; p < 2; p++) {
            float acc = b1[tid];
            #pragma unroll
            for (int i = 0; i < 21; i++) acc = fmaf(fmaxf(KMs[p][i], 0.0f), W1[i*10 + tid], acc);
            x1s[p][tid] = acc;
        }
    }
    __syncthreads();
    if (tid < 5) {
        for (int p = 0; p < 2; p++) {
            float acc = b2[tid];
            #pragma unroll
            for (int i = 0; i < 10; i++) acc = fmaf(fmaxf(x1s[p][i], 0.0f), W2[i*5 + tid], acc);
            x2s[p][tid] = acc;
        }
    }
    __syncthreads();
    if (tid == 0) {
        float lv[2];
        for (int p = 0; p < 2; p++) {
            float acc = b3[0];
            #pragma unroll
            for (int i = 0; i < 5; i++) acc = fmaf(fmaxf(x2s[p][i], 0.0f), W3[i], acc);
            lv[p] = acc;
        }
        out[bb] = 1.0f / (1.0f + expf(lv[1] - lv[0]));   // sigmoid(l1 - l2)
    }
}

extern "C" void kernel_launch(void* const* d_in, const int* in_sizes, int n_in,
                              void* d_out, int out_size, void* d_ws, size_t ws_size,
                              hipStream_t stream)
{
    const int*   q1  = (const int*)  d_in[0];
    const int*   d1  = (const int*)  d_in[1];
    const int*   q2  = (const int*)  d_in[2];
    const int*   d2  = (const int*)  d_in[3];
    const float* emb = (const float*)d_in[4];
    const float* W1  = (const float*)d_in[5];
    const float* b1  = (const float*)d_in[6];
    const float* W2  = (const float*)d_in[7];
    const float* b2  = (const float*)d_in[8];
    const float* W3  = (const float*)d_in[9];
    const float* b3  = (const float*)d_in[10];
    float* out = (float*)d_out;
    (void)in_sizes; (void)n_in; (void)d_ws; (void)ws_size;

    knrm_kernel<<<out_size, 256, 0, stream>>>(q1, d1, q2, d2, emb, W1, b1, W2, b2, W3, b3, out);
}

// Round 6
// 147.211 us; speedup vs baseline: 1.5288x; 1.5288x over previous
//
#include <hip/hip_runtime.h>

// KNRM forward, MI355X (gfx950). R5.
// R4 post-mortem: reg-staged prefetch spilled (263MB scratch). Root cause across
// R0-R4: staging needs VGPRs (gather+normalize+split) and the live-set doesn't fit;
// no-spill configs are latency-exposed instead. R5: move normalize+bf16-split to a
// one-shot precompute kernel (bf16 hi/lo tables in d_ws), then stage via
// global_load_lds (ZERO staging VGPRs) with the LDS swizzle folded into the
// per-lane GLOBAL address (linear LDS dest, m173 pattern). 32-row chunks,
// double-buffered: issue chunk c+1 loads right after the barrier, compute chunk c.
// Fallback (ws too small): in-kernel normalize, same loop shape, synchronous.

typedef __attribute__((ext_vector_type(8))) short bf16x8;
typedef __attribute__((ext_vector_type(4))) float f32x4;

__device__ __forceinline__ unsigned short f2bf(float f) {   // RNE float->bf16
    unsigned u = __float_as_uint(f);
    u += 0x7fffu + ((u >> 16) & 1u);
    return (unsigned short)(u >> 16);
}
__device__ __forceinline__ float bf2f(unsigned short h) {
    return __uint_as_float(((unsigned)h) << 16);
}

// ---- precompute: normalized bf16 hi/lo tables, row-major [vocab][128] ----
__global__ __launch_bounds__(256)
void norm_split_kernel(const float* __restrict__ emb,
                       unsigned short* __restrict__ th,
                       unsigned short* __restrict__ tl, int vocab)
{
    const int row = blockIdx.x * 8 + (threadIdx.x >> 5);
    if (row >= vocab) return;
    const int ln = threadIdx.x & 31;
    const float4 v = *reinterpret_cast<const float4*>(emb + (size_t)row * 128 + ln * 4);
    float ss = v.x*v.x + v.y*v.y + v.z*v.z + v.w*v.w;
    #pragma unroll
    for (int m = 16; m >= 1; m >>= 1) ss += __shfl_xor(ss, m);   // 32-lane row reduce
    const float rn = 1.0f / (sqrtf(ss) + 1e-13f);                // reference eps
    const float f0 = v.x*rn, f1 = v.y*rn, f2 = v.z*rn, f3 = v.w*rn;
    const unsigned short h0 = f2bf(f0), h1 = f2bf(f1), h2 = f2bf(f2), h3 = f2bf(f3);
    const unsigned short g0 = f2bf(f0 - bf2f(h0)), g1 = f2bf(f1 - bf2f(h1));
    const unsigned short g2 = f2bf(f2 - bf2f(h2)), g3 = f2bf(f3 - bf2f(h3));
    const int off = row * 128 + ln * 4;
    *reinterpret_cast<uint2*>(th + off) =
        make_uint2((unsigned)h0 | ((unsigned)h1 << 16), (unsigned)h2 | ((unsigned)h3 << 16));
    *reinterpret_cast<uint2*>(tl + off) =
        make_uint2((unsigned)g0 | ((unsigned)g1 << 16), (unsigned)g2 | ((unsigned)g3 << 16));
}

// ---- global_load_lds helper: 16B per lane, linear LDS dest (base + lane*16) ----
__device__ __forceinline__ void glds16(const unsigned short* g, unsigned short* l) {
    __builtin_amdgcn_global_load_lds((const __attribute__((address_space(1))) void*)g,
                                     (__attribute__((address_space(3))) void*)l, 16, 0, 0);
}

// PRE staging, d-chunk: wave w stages its 8 rows of a 32-row chunk from the bf16
// tables. Swizzle (chunk slot s holds global chunk s^(r&15)) via per-lane global addr.
__device__ __forceinline__ void stage_pre_d(const unsigned short* __restrict__ th,
                                            const unsigned short* __restrict__ tl,
                                            const int* __restrict__ ids, int base,
                                            unsigned short* __restrict__ dh,
                                            unsigned short* __restrict__ dl,
                                            int w, int l)
{
    #pragma unroll
    for (int j = 0; j < 2; j++) {
        const int r   = 8*w + 4*j + (l >> 4);            // buffer row 0..31
        const int id  = ids[base + r];                   // LDS broadcast read
        const int gsw = ((l & 15) ^ (r & 15)) << 3;      // swizzled global elem offset
        glds16(th + (size_t)id * 128 + gsw, dh + (8*w + 4*j) * 128);
        glds16(tl + (size_t)id * 128 + gsw, dl + (8*w + 4*j) * 128);
    }
}

// PRE staging, q (64 rows across both buffers): wave w stages global q rows 16w..16w+15.
__device__ __forceinline__ void stage_pre_q(const unsigned short* __restrict__ th,
                                            const unsigned short* __restrict__ tl,
                                            const int* __restrict__ qids,
                                            unsigned short (&BH)[2][32*128],
                                            unsigned short (&BL)[2][32*128],
                                            int w, int l)
{
    unsigned short* dh = BH[w >> 1];
    unsigned short* dl = BL[w >> 1];
    const int rb = (w & 1) * 16;
    #pragma unroll
    for (int j = 0; j < 4; j++) {
        const int r   = rb + 4*j + (l >> 4);             // buffer row
        const int id  = qids[(w >> 1) * 32 + r];         // global q row = (w>=2)*32 + r
        const int gsw = ((l & 15) ^ (r & 15)) << 3;
        glds16(th + (size_t)id * 128 + gsw, dh + (rb + 4*j) * 128);
        glds16(tl + (size_t)id * 128 + gsw, dl + (rb + 4*j) * 128);
    }
}

// Fallback staging: gather f32, normalize, split, swizzled LDS write (32 rows).
__device__ __forceinline__ void stage_f32(const float* __restrict__ emb,
                                          const int* __restrict__ ids,
                                          unsigned short* __restrict__ hi,
                                          unsigned short* __restrict__ lo,
                                          int tid)
{
    const int lg = tid >> 5;
    const int ln = tid & 31;
    #pragma unroll
    for (int i = 0; i < 4; i++) {
        const int row = i * 8 + lg;                      // 0..31
        const int id  = ids[row];
        const float4 v = *reinterpret_cast<const float4*>(emb + (size_t)id * 128 + ln * 4);
        float ss = v.x*v.x + v.y*v.y + v.z*v.z + v.w*v.w;
        #pragma unroll
        for (int m = 16; m >= 1; m >>= 1) ss += __shfl_xor(ss, m);
        const float rn = 1.0f / (sqrtf(ss) + 1e-13f);
        const float f0 = v.x*rn, f1 = v.y*rn, f2 = v.z*rn, f3 = v.w*rn;
        const unsigned short h0 = f2bf(f0), h1 = f2bf(f1), h2 = f2bf(f2), h3 = f2bf(f3);
        const unsigned short g0 = f2bf(f0 - bf2f(h0)), g1 = f2bf(f1 - bf2f(h1));
        const unsigned short g2 = f2bf(f2 - bf2f(h2)), g3 = f2bf(f3 - bf2f(h3));
        const int off = row*128 + (((ln >> 1) ^ (row & 15)) << 3) + ((ln & 1) << 2);
        *reinterpret_cast<uint2*>(hi + off) =
            make_uint2((unsigned)h0 | ((unsigned)h1 << 16), (unsigned)h2 | ((unsigned)h3 << 16));
        *reinterpret_cast<uint2*>(lo + off) =
            make_uint2((unsigned)g0 | ((unsigned)g1 << 16), (unsigned)g2 | ((unsigned)g3 << 16));
    }
}

// 21 kernel contributions of one matching value m; sp[i] accumulates true k_i.
// Geometric ladder: k_{10+j} = t0*R^j*e^{-j(j+1)/2}, k_{10-j} = t0*R^-j*e^{-j(j-1)/2}.
__device__ __forceinline__ void apply_el(float m, float (&sp)[21]) {
    const float dm = m - 0.05f;
    const float x  = m * 14.426950408889634f;                                // 10*log2(e)*m
    const float t0 = __builtin_amdgcn_exp2f(dm * dm * -72.13475204444817f);  // k_10
    const float R  = __builtin_amdgcn_exp2f(x);                              // e^{10m}
    const float Ri = __builtin_amdgcn_exp2f(-x);                             // e^{-10m}
    sp[10] += t0;
    float tu = t0;
    tu *= R;  sp[11] = fmaf(tu, 3.6787944117e-1f,  sp[11]);  // e^-1
    tu *= R;  sp[12] = fmaf(tu, 4.9787068368e-2f,  sp[12]);  // e^-3
    tu *= R;  sp[13] = fmaf(tu, 2.4787521767e-3f,  sp[13]);  // e^-6
    tu *= R;  sp[14] = fmaf(tu, 4.5399929762e-5f,  sp[14]);  // e^-10
    tu *= R;  sp[15] = fmaf(tu, 3.0590232050e-7f,  sp[15]);  // e^-15
    tu *= R;  sp[16] = fmaf(tu, 7.5825604279e-10f, sp[16]);  // e^-21
    tu *= R;  sp[17] = fmaf(tu, 6.9144001069e-13f, sp[17]);  // e^-28
    tu *= R;  sp[18] = fmaf(tu, 2.3195228302e-16f, sp[18]);  // e^-36
    tu *= R;  sp[19] = fmaf(tu, 2.8625185805e-20f, sp[19]);  // e^-45
    float td = t0;
    td *= Ri; sp[9] += td;                                   // e^0
    td *= Ri; sp[8] = fmaf(td, 3.6787944117e-1f,  sp[8]);    // e^-1
    td *= Ri; sp[7] = fmaf(td, 4.9787068368e-2f,  sp[7]);    // e^-3
    td *= Ri; sp[6] = fmaf(td, 2.4787521767e-3f,  sp[6]);    // e^-6
    td *= Ri; sp[5] = fmaf(td, 4.5399929762e-5f,  sp[5]);    // e^-10
    td *= Ri; sp[4] = fmaf(td, 3.0590232050e-7f,  sp[4]);    // e^-15
    td *= Ri; sp[3] = fmaf(td, 7.5825604279e-10f, sp[3]);    // e^-21
    td *= Ri; sp[2] = fmaf(td, 6.9144001069e-13f, sp[2]);    // e^-28
    td *= Ri; sp[1] = fmaf(td, 2.3195228302e-16f, sp[1]);    // e^-36
    td *= Ri; sp[0] = fmaf(td, 2.8625185805e-20f, sp[0]);    // e^-45
    const float e = m - 1.0f;                                // exact-match (sigma=1e-3)
    sp[20] += __builtin_amdgcn_exp2f(e * e * -721347.5204444817f);
}

template<bool PRE>
__global__ __launch_bounds__(256, 2)
void knrm_kernel(const int* __restrict__ q1, const int* __restrict__ d1,
                 const int* __restrict__ q2, const int* __restrict__ d2,
                 const float* __restrict__ emb,
                 const unsigned short* __restrict__ th, const unsigned short* __restrict__ tl,
                 const float* __restrict__ W1, const float* __restrict__ b1,
                 const float* __restrict__ W2, const float* __restrict__ b2,
                 const float* __restrict__ W3, const float* __restrict__ b3,
                 float* __restrict__ out)
{
    __shared__ unsigned short bh[2][32*128];   // 8KB each buffer half (hi)
    __shared__ unsigned short bl[2][32*128];   // 8KB each (lo)
    __shared__ int   sh_ids[256];
    __shared__ float S[64][21];
    __shared__ float KMs[2][21];
    __shared__ float x1s[2][10], x2s[2][5];

    const int tid = threadIdx.x;
    const int bb  = blockIdx.x;
    const int w   = tid >> 6;     // wave 0..3 -> q rows 16w..16w+15
    const int l   = tid & 63;
    const int lr  = l & 15;       // MFMA row-in-tile (A) / col=q (B,C)
    const int lh  = l >> 4;       // k-group

    for (int p = 0; p < 2; p++) {
        const int* qids = (p == 0 ? q1 : q2) + bb * 64;
        const int* dids = (p == 0 ? d1 : d2) + bb * 256;

        sh_ids[tid] = dids[tid];
        if (PRE) {
            stage_pre_q(th, tl, qids, bh, bl, w, l);
        } else {
            stage_f32(emb, qids,      bh[0], bl[0], tid);
            stage_f32(emb, qids + 32, bh[1], bl[1], tid);
        }
        __syncthreads();                                 // q + sh_ids visible

        // Hoist B (q-side) fragments to registers for the whole pass.
        bf16x8 Bh[4], Bl[4];
        const int qb = w >> 1;
        const int qr = (w * 16 + lr) & 31;               // buffer row; qr&15 == lr
        #pragma unroll
        for (int ks = 0; ks < 4; ks++) {
            const int off = qr*128 + (((ks*4 + lh) ^ lr) << 3);
            Bh[ks] = *reinterpret_cast<const bf16x8*>(&bh[qb][off]);
            Bl[ks] = *reinterpret_cast<const bf16x8*>(&bl[qb][off]);
        }
        __syncthreads();                                 // B hoisted, buffers free

        float sp[21];
        #pragma unroll
        for (int i = 0; i < 21; i++) sp[i] = 0.0f;

        if (PRE) stage_pre_d(th, tl, sh_ids, 0, bh[0], bl[0], w, l);   // chunk 0 in flight

        for (int c = 0; c < 8; c++) {
            if (!PRE) stage_f32(emb, dids + c * 32, bh[c & 1], bl[c & 1], tid);
            __syncthreads();                             // chunk c ready (vmcnt drained)
            if (PRE && c < 7)                            // chunk c+1 flies under compute c
                stage_pre_d(th, tl, sh_ids, (c + 1) * 32, bh[(c + 1) & 1], bl[(c + 1) & 1], w, l);

            const unsigned short* ch = bh[c & 1];
            const unsigned short* cl = bl[c & 1];
            f32x4 C0 = {0.f,0.f,0.f,0.f}, C1 = {0.f,0.f,0.f,0.f};
            #pragma unroll
            for (int ks = 0; ks < 4; ks++) {
                const int o0 = lr*128        + (((ks*4 + lh) ^ lr) << 3);
                const int o1 = (16 + lr)*128 + (((ks*4 + lh) ^ lr) << 3);
                const bf16x8 A0h = *reinterpret_cast<const bf16x8*>(ch + o0);
                const bf16x8 A0l = *reinterpret_cast<const bf16x8*>(cl + o0);
                const bf16x8 A1h = *reinterpret_cast<const bf16x8*>(ch + o1);
                const bf16x8 A1l = *reinterpret_cast<const bf16x8*>(cl + o1);
                C0 = __builtin_amdgcn_mfma_f32_16x16x32_bf16(A0h, Bh[ks], C0, 0, 0, 0);
                C1 = __builtin_amdgcn_mfma_f32_16x16x32_bf16(A1h, Bh[ks], C1, 0, 0, 0);
                C0 = __builtin_amdgcn_mfma_f32_16x16x32_bf16(A0h, Bl[ks], C0, 0, 0, 0);
                C1 = __builtin_amdgcn_mfma_f32_16x16x32_bf16(A1h, Bl[ks], C1, 0, 0, 0);
                C0 = __builtin_amdgcn_mfma_f32_16x16x32_bf16(A0l, Bh[ks], C0, 0, 0, 0);
                C1 = __builtin_amdgcn_mfma_f32_16x16x32_bf16(A1l, Bh[ks], C1, 0, 0, 0);
            }
            #pragma unroll
            for (int r = 0; r < 4; r++) { apply_el(C0[r], sp); apply_el(C1[r], sp); }
        }

        // Reduce sp over the 4 lanes sharing a q column (sp holds true k sums).
        #pragma unroll
        for (int i = 0; i < 21; i++) {
            float t = sp[i];
            t += __shfl_xor(t, 16);
            t += __shfl_xor(t, 32);
            sp[i] = t;
        }
        if (l < 16) {
            #pragma unroll
            for (int i = 0; i < 21; i++) S[w*16 + l][i] = sp[i];
        }
        __syncthreads();   // S visible; also orders chunk-7 reads before next-pass staging

        if (tid < 64) {    // wave 0: KM_i = sum_q log1p(S[q][i])
            #pragma unroll
            for (int i = 0; i < 21; i++) {
                float t = log1pf(S[tid][i]);
                #pragma unroll
                for (int m = 1; m <= 32; m <<= 1) t += __shfl_xor(t, m);
                if (tid == 0) KMs[p][i] = t;
            }
        }
    }

    // tiny MLP (relu before each linear) + sigmoid(l1 - l2)
    __syncthreads();
    if (tid < 10) {
        for (int p = 0; p < 2; p++) {
            float acc = b1[tid];
            #pragma unroll
            for (int i = 0; i < 21; i++) acc = fmaf(fmaxf(KMs[p][i], 0.0f), W1[i*10 + tid], acc);
            x1s[p][tid] = acc;
        }
    }
    __syncthreads();
    if (tid < 5) {
        for (int p = 0; p < 2; p++) {
            float acc = b2[tid];
            #pragma unroll
            for (int i = 0; i < 10; i++) acc = fmaf(fmaxf(x1s[p][i], 0.0f), W2[i*5 + tid], acc);
            x2s[p][tid] = acc;
        }
    }
    __syncthreads();
    if (tid == 0) {
        float lv[2];
        for (int p = 0; p < 2; p++) {
            float acc = b3[0];
            #pragma unroll
            for (int i = 0; i < 5; i++) acc = fmaf(fmaxf(x2s[p][i], 0.0f), W3[i], acc);
            lv[p] = acc;
        }
        out[bb] = 1.0f / (1.0f + expf(lv[1] - lv[0]));   // sigmoid(l1 - l2)
    }
}

extern "C" void kernel_launch(void* const* d_in, const int* in_sizes, int n_in,
                              void* d_out, int out_size, void* d_ws, size_t ws_size,
                              hipStream_t stream)
{
    const int*   q1  = (const int*)  d_in[0];
    const int*   d1  = (const int*)  d_in[1];
    const int*   q2  = (const int*)  d_in[2];
    const int*   d2  = (const int*)  d_in[3];
    const float* emb = (const float*)d_in[4];
    const float* W1  = (const float*)d_in[5];
    const float* b1  = (const float*)d_in[6];
    const float* W2  = (const float*)d_in[7];
    const float* b2  = (const float*)d_in[8];
    const float* W3  = (const float*)d_in[9];
    const float* b3  = (const float*)d_in[10];
    float* out = (float*)d_out;
    (void)n_in;

    const int vocab = in_sizes[4] / 128;
    const size_t need = (size_t)vocab * 128 * 2 * 2;     // hi + lo bf16 tables

    if (ws_size >= need) {
        unsigned short* th = (unsigned short*)d_ws;
        unsigned short* tl = th + (size_t)vocab * 128;
        norm_split_kernel<<<(vocab + 7) / 8, 256, 0, stream>>>(emb, th, tl, vocab);
        knrm_kernel<true><<<out_size, 256, 0, stream>>>(q1, d1, q2, d2, emb, th, tl,
                                                        W1, b1, W2, b2, W3, b3, out);
    } else {
        knrm_kernel<false><<<out_size, 256, 0, stream>>>(q1, d1, q2, d2, emb, nullptr, nullptr,
                                                         W1, b1, W2, b2, W3, b3, out);
    }
}

// Round 7
// 138.589 us; speedup vs baseline: 1.6239x; 1.0622x over previous
//
#include <hip/hip_runtime.h>

// KNRM forward, MI355X (gfx950). R6.
// R5 (kept): precomputed normalized bf16 hi/lo tables in d_ws; global_load_lds
// staging (zero staging VGPRs), swizzle folded into per-lane global address,
// 32-row double-buffered chunks; no spill (VGPR 116, WRITE_SIZE 32KB).
// R6: VALU is the dominant measured consumer (40% busy = 55us issue). Pack the
// kernel ladder 2 elements wide using f32x2 ext-vectors (+__builtin_elementwise_fma)
// so the backend emits v_pk_mul_f32/v_pk_fma_f32 (gfx90a+): ~2.5x fewer issue
// slots in apply. sp becomes packed f32x2[21] (reduced .x+.y at pass end).

typedef __attribute__((ext_vector_type(8))) short bf16x8;
typedef __attribute__((ext_vector_type(4))) float f32x4;
typedef __attribute__((ext_vector_type(2))) float f32x2;

__device__ __forceinline__ unsigned short f2bf(float f) {   // RNE float->bf16
    unsigned u = __float_as_uint(f);
    u += 0x7fffu + ((u >> 16) & 1u);
    return (unsigned short)(u >> 16);
}
__device__ __forceinline__ float bf2f(unsigned short h) {
    return __uint_as_float(((unsigned)h) << 16);
}

// ---- precompute: normalized bf16 hi/lo tables, row-major [vocab][128] ----
__global__ __launch_bounds__(256)
void norm_split_kernel(const float* __restrict__ emb,
                       unsigned short* __restrict__ th,
                       unsigned short* __restrict__ tl, int vocab)
{
    const int row = blockIdx.x * 8 + (threadIdx.x >> 5);
    if (row >= vocab) return;
    const int ln = threadIdx.x & 31;
    const float4 v = *reinterpret_cast<const float4*>(emb + (size_t)row * 128 + ln * 4);
    float ss = v.x*v.x + v.y*v.y + v.z*v.z + v.w*v.w;
    #pragma unroll
    for (int m = 16; m >= 1; m >>= 1) ss += __shfl_xor(ss, m);   // 32-lane row reduce
    const float rn = 1.0f / (sqrtf(ss) + 1e-13f);                // reference eps
    const float f0 = v.x*rn, f1 = v.y*rn, f2 = v.z*rn, f3 = v.w*rn;
    const unsigned short h0 = f2bf(f0), h1 = f2bf(f1), h2 = f2bf(f2), h3 = f2bf(f3);
    const unsigned short g0 = f2bf(f0 - bf2f(h0)), g1 = f2bf(f1 - bf2f(h1));
    const unsigned short g2 = f2bf(f2 - bf2f(h2)), g3 = f2bf(f3 - bf2f(h3));
    const int off = row * 128 + ln * 4;
    *reinterpret_cast<uint2*>(th + off) =
        make_uint2((unsigned)h0 | ((unsigned)h1 << 16), (unsigned)h2 | ((unsigned)h3 << 16));
    *reinterpret_cast<uint2*>(tl + off) =
        make_uint2((unsigned)g0 | ((unsigned)g1 << 16), (unsigned)g2 | ((unsigned)g3 << 16));
}

// ---- global_load_lds helper: 16B per lane, linear LDS dest (base + lane*16) ----
__device__ __forceinline__ void glds16(const unsigned short* g, unsigned short* l) {
    __builtin_amdgcn_global_load_lds((const __attribute__((address_space(1))) void*)g,
                                     (__attribute__((address_space(3))) void*)l, 16, 0, 0);
}

// PRE staging, d-chunk: wave w stages its 8 rows of a 32-row chunk from the bf16
// tables. Swizzle (chunk slot s holds global chunk s^(r&15)) via per-lane global addr.
__device__ __forceinline__ void stage_pre_d(const unsigned short* __restrict__ th,
                                            const unsigned short* __restrict__ tl,
                                            const int* __restrict__ ids, int base,
                                            unsigned short* __restrict__ dh,
                                            unsigned short* __restrict__ dl,
                                            int w, int l)
{
    #pragma unroll
    for (int j = 0; j < 2; j++) {
        const int r   = 8*w + 4*j + (l >> 4);            // buffer row 0..31
        const int id  = ids[base + r];                   // LDS broadcast read
        const int gsw = ((l & 15) ^ (r & 15)) << 3;      // swizzled global elem offset
        glds16(th + (size_t)id * 128 + gsw, dh + (8*w + 4*j) * 128);
        glds16(tl + (size_t)id * 128 + gsw, dl + (8*w + 4*j) * 128);
    }
}

// PRE staging, q (64 rows across both buffers): wave w stages global q rows 16w..16w+15.
__device__ __forceinline__ void stage_pre_q(const unsigned short* __restrict__ th,
                                            const unsigned short* __restrict__ tl,
                                            const int* __restrict__ qids,
                                            unsigned short (&BH)[2][32*128],
                                            unsigned short (&BL)[2][32*128],
                                            int w, int l)
{
    unsigned short* dh = BH[w >> 1];
    unsigned short* dl = BL[w >> 1];
    const int rb = (w & 1) * 16;
    #pragma unroll
    for (int j = 0; j < 4; j++) {
        const int r   = rb + 4*j + (l >> 4);             // buffer row
        const int id  = qids[(w >> 1) * 32 + r];         // global q row = (w>=2)*32 + r
        const int gsw = ((l & 15) ^ (r & 15)) << 3;
        glds16(th + (size_t)id * 128 + gsw, dh + (rb + 4*j) * 128);
        glds16(tl + (size_t)id * 128 + gsw, dl + (rb + 4*j) * 128);
    }
}

// Fallback staging: gather f32, normalize, split, swizzled LDS write (32 rows).
__device__ __forceinline__ void stage_f32(const float* __restrict__ emb,
                                          const int* __restrict__ ids,
                                          unsigned short* __restrict__ hi,
                                          unsigned short* __restrict__ lo,
                                          int tid)
{
    const int lg = tid >> 5;
    const int ln = tid & 31;
    #pragma unroll
    for (int i = 0; i < 4; i++) {
        const int row = i * 8 + lg;                      // 0..31
        const int id  = ids[row];
        const float4 v = *reinterpret_cast<const float4*>(emb + (size_t)id * 128 + ln * 4);
        float ss = v.x*v.x + v.y*v.y + v.z*v.z + v.w*v.w;
        #pragma unroll
        for (int m = 16; m >= 1; m >>= 1) ss += __shfl_xor(ss, m);
        const float rn = 1.0f / (sqrtf(ss) + 1e-13f);
        const float f0 = v.x*rn, f1 = v.y*rn, f2 = v.z*rn, f3 = v.w*rn;
        const unsigned short h0 = f2bf(f0), h1 = f2bf(f1), h2 = f2bf(f2), h3 = f2bf(f3);
        const unsigned short g0 = f2bf(f0 - bf2f(h0)), g1 = f2bf(f1 - bf2f(h1));
        const unsigned short g2 = f2bf(f2 - bf2f(h2)), g3 = f2bf(f3 - bf2f(h3));
        const int off = row*128 + (((ln >> 1) ^ (row & 15)) << 3) + ((ln & 1) << 2);
        *reinterpret_cast<uint2*>(hi + off) =
            make_uint2((unsigned)h0 | ((unsigned)h1 << 16), (unsigned)h2 | ((unsigned)h3 << 16));
        *reinterpret_cast<uint2*>(lo + off) =
            make_uint2((unsigned)g0 | ((unsigned)g1 << 16), (unsigned)g2 | ((unsigned)g3 << 16));
    }
}

#define PKF(a, b, c) __builtin_elementwise_fma((a), (b), (c))

// 21 kernel contributions of an element PAIR (m0,m1); sp[i] packed {elem0, elem1}.
// Geometric ladder: k_{10+j} = t0*R^j*e^{-j(j+1)/2}, k_{10-j} = t0*R^-j*e^{-j(j-1)/2}.
__device__ __forceinline__ void apply_pair(float m0, float m1, f32x2 (&sp)[21]) {
    const f32x2 m2 = {m0, m1};
    const f32x2 dm = m2 - 0.05f;
    const f32x2 ta = (dm * dm) * -72.13475204444817f;            // -50*log2e*(m-.05)^2
    const f32x2 x2 = m2 * 14.426950408889634f;                   // 10*log2e*m
    const f32x2 t0 = { __builtin_amdgcn_exp2f(ta[0]), __builtin_amdgcn_exp2f(ta[1]) };
    const f32x2 R  = { __builtin_amdgcn_exp2f(x2[0]), __builtin_amdgcn_exp2f(x2[1]) };
    const f32x2 Ri = { __builtin_amdgcn_exp2f(-x2[0]), __builtin_amdgcn_exp2f(-x2[1]) };
    sp[10] += t0;
    f32x2 tu = t0;
    tu *= R;  sp[11] = PKF(tu, (f32x2)3.6787944117e-1f,  sp[11]);  // e^-1
    tu *= R;  sp[12] = PKF(tu, (f32x2)4.9787068368e-2f,  sp[12]);  // e^-3
    tu *= R;  sp[13] = PKF(tu, (f32x2)2.4787521767e-3f,  sp[13]);  // e^-6
    tu *= R;  sp[14] = PKF(tu, (f32x2)4.5399929762e-5f,  sp[14]);  // e^-10
    tu *= R;  sp[15] = PKF(tu, (f32x2)3.0590232050e-7f,  sp[15]);  // e^-15
    tu *= R;  sp[16] = PKF(tu, (f32x2)7.5825604279e-10f, sp[16]);  // e^-21
    tu *= R;  sp[17] = PKF(tu, (f32x2)6.9144001069e-13f, sp[17]);  // e^-28
    tu *= R;  sp[18] = PKF(tu, (f32x2)2.3195228302e-16f, sp[18]);  // e^-36
    tu *= R;  sp[19] = PKF(tu, (f32x2)2.8625185805e-20f, sp[19]);  // e^-45
    f32x2 td = t0;
    td *= Ri; sp[9] += td;                                         // e^0
    td *= Ri; sp[8] = PKF(td, (f32x2)3.6787944117e-1f,  sp[8]);    // e^-1
    td *= Ri; sp[7] = PKF(td, (f32x2)4.9787068368e-2f,  sp[7]);    // e^-3
    td *= Ri; sp[6] = PKF(td, (f32x2)2.4787521767e-3f,  sp[6]);    // e^-6
    td *= Ri; sp[5] = PKF(td, (f32x2)4.5399929762e-5f,  sp[5]);    // e^-10
    td *= Ri; sp[4] = PKF(td, (f32x2)3.0590232050e-7f,  sp[4]);    // e^-15
    td *= Ri; sp[3] = PKF(td, (f32x2)7.5825604279e-10f, sp[3]);    // e^-21
    td *= Ri; sp[2] = PKF(td, (f32x2)6.9144001069e-13f, sp[2]);    // e^-28
    td *= Ri; sp[1] = PKF(td, (f32x2)2.3195228302e-16f, sp[1]);    // e^-36
    td *= Ri; sp[0] = PKF(td, (f32x2)2.8625185805e-20f, sp[0]);    // e^-45
    const f32x2 e  = m2 - 1.0f;                                    // exact-match (sigma=1e-3)
    const f32x2 ea = (e * e) * -721347.5204444817f;
    const f32x2 ex = { __builtin_amdgcn_exp2f(ea[0]), __builtin_amdgcn_exp2f(ea[1]) };
    sp[20] += ex;
}

template<bool PRE>
__global__ __launch_bounds__(256, 2)
void knrm_kernel(const int* __restrict__ q1, const int* __restrict__ d1,
                 const int* __restrict__ q2, const int* __restrict__ d2,
                 const float* __restrict__ emb,
                 const unsigned short* __restrict__ th, const unsigned short* __restrict__ tl,
                 const float* __restrict__ W1, const float* __restrict__ b1,
                 const float* __restrict__ W2, const float* __restrict__ b2,
                 const float* __restrict__ W3, const float* __restrict__ b3,
                 float* __restrict__ out)
{
    __shared__ unsigned short bh[2][32*128];   // 8KB each buffer half (hi)
    __shared__ unsigned short bl[2][32*128];   // 8KB each (lo)
    __shared__ int   sh_ids[256];
    __shared__ float S[64][21];
    __shared__ float KMs[2][21];
    __shared__ float x1s[2][10], x2s[2][5];

    const int tid = threadIdx.x;
    const int bb  = blockIdx.x;
    const int w   = tid >> 6;     // wave 0..3 -> q rows 16w..16w+15
    const int l   = tid & 63;
    const int lr  = l & 15;       // MFMA row-in-tile (A) / col=q (B,C)
    const int lh  = l >> 4;       // k-group

    for (int p = 0; p < 2; p++) {
        const int* qids = (p == 0 ? q1 : q2) + bb * 64;
        const int* dids = (p == 0 ? d1 : d2) + bb * 256;

        sh_ids[tid] = dids[tid];
        if (PRE) {
            stage_pre_q(th, tl, qids, bh, bl, w, l);
        } else {
            stage_f32(emb, qids,      bh[0], bl[0], tid);
            stage_f32(emb, qids + 32, bh[1], bl[1], tid);
        }
        __syncthreads();                                 // q + sh_ids visible

        // Hoist B (q-side) fragments to registers for the whole pass.
        bf16x8 Bh[4], Bl[4];
        const int qb = w >> 1;
        const int qr = (w * 16 + lr) & 31;               // buffer row; qr&15 == lr
        #pragma unroll
        for (int ks = 0; ks < 4; ks++) {
            const int off = qr*128 + (((ks*4 + lh) ^ lr) << 3);
            Bh[ks] = *reinterpret_cast<const bf16x8*>(&bh[qb][off]);
            Bl[ks] = *reinterpret_cast<const bf16x8*>(&bl[qb][off]);
        }
        __syncthreads();                                 // B hoisted, buffers free

        f32x2 sp[21];
        #pragma unroll
        for (int i = 0; i < 21; i++) sp[i] = (f32x2){0.f, 0.f};

        if (PRE) stage_pre_d(th, tl, sh_ids, 0, bh[0], bl[0], w, l);   // chunk 0 in flight

        for (int c = 0; c < 8; c++) {
            if (!PRE) stage_f32(emb, dids + c * 32, bh[c & 1], bl[c & 1], tid);
            __syncthreads();                             // chunk c ready (vmcnt drained)
            if (PRE && c < 7)                            // chunk c+1 flies under compute c
                stage_pre_d(th, tl, sh_ids, (c + 1) * 32, bh[(c + 1) & 1], bl[(c + 1) & 1], w, l);

            const unsigned short* ch = bh[c & 1];
            const unsigned short* cl = bl[c & 1];
            f32x4 C0 = {0.f,0.f,0.f,0.f}, C1 = {0.f,0.f,0.f,0.f};
            #pragma unroll
            for (int ks = 0; ks < 4; ks++) {
                const int o0 = lr*128        + (((ks*4 + lh) ^ lr) << 3);
                const int o1 = (16 + lr)*128 + (((ks*4 + lh) ^ lr) << 3);
                const bf16x8 A0h = *reinterpret_cast<const bf16x8*>(ch + o0);
                const bf16x8 A0l = *reinterpret_cast<const bf16x8*>(cl + o0);
                const bf16x8 A1h = *reinterpret_cast<const bf16x8*>(ch + o1);
                const bf16x8 A1l = *reinterpret_cast<const bf16x8*>(cl + o1);
                C0 = __builtin_amdgcn_mfma_f32_16x16x32_bf16(A0h, Bh[ks], C0, 0, 0, 0);
                C1 = __builtin_amdgcn_mfma_f32_16x16x32_bf16(A1h, Bh[ks], C1, 0, 0, 0);
                C0 = __builtin_amdgcn_mfma_f32_16x16x32_bf16(A0h, Bl[ks], C0, 0, 0, 0);
                C1 = __builtin_amdgcn_mfma_f32_16x16x32_bf16(A1h, Bl[ks], C1, 0, 0, 0);
                C0 = __builtin_amdgcn_mfma_f32_16x16x32_bf16(A0l, Bh[ks], C0, 0, 0, 0);
                C1 = __builtin_amdgcn_mfma_f32_16x16x32_bf16(A1l, Bh[ks], C1, 0, 0, 0);
            }
            #pragma unroll
            for (int r = 0; r < 4; r++) apply_pair(C0[r], C1[r], sp);
        }

        // Reduce packed halves, then over the 4 lanes sharing a q column.
        float sps[21];
        #pragma unroll
        for (int i = 0; i < 21; i++) {
            float t = sp[i][0] + sp[i][1];
            t += __shfl_xor(t, 16);
            t += __shfl_xor(t, 32);
            sps[i] = t;
        }
        if (l < 16) {
            #pragma unroll
            for (int i = 0; i < 21; i++) S[w*16 + l][i] = sps[i];
        }
        __syncthreads();   // S visible; also orders chunk-7 reads before next-pass staging

        if (tid < 64) {    // wave 0: KM_i = sum_q log1p(S[q][i])
            #pragma unroll
            for (int i = 0; i < 21; i++) {
                float t = log1pf(S[tid][i]);
                #pragma unroll
                for (int m = 1; m <= 32; m <<= 1) t += __shfl_xor(t, m);
                if (tid == 0) KMs[p][i] = t;
            }
        }
    }

    // tiny MLP (relu before each linear) + sigmoid(l1 - l2)
    __syncthreads();
    if (tid < 10) {
        for (int p = 0; p < 2; p++) {
            float acc = b1[tid];
            #pragma unroll
            for (int i = 0; i < 21; i++) acc = fmaf(fmaxf(KMs[p][i], 0.0f), W1[i*10 + tid], acc);
            x1s[p][tid] = acc;
        }
    }
    __syncthreads();
    if (tid < 5) {
        for (int p = 0; p < 2; p++) {
            float acc = b2[tid];
            #pragma unroll
            for (int i = 0; i < 10; i++) acc = fmaf(fmaxf(x1s[p][i], 0.0f), W2[i*5 + tid], acc);
            x2s[p][tid] = acc;
        }
    }
    __syncthreads();
    if (tid == 0) {
        float lv[2];
        for (int p = 0; p < 2; p++) {
            float acc = b3[0];
            #pragma unroll
            for (int i = 0; i < 5; i++) acc = fmaf(fmaxf(x2s[p][i], 0.0f), W3[i], acc);
            lv[p] = acc;
        }
        out[bb] = 1.0f / (1.0f + expf(lv[1] - lv[0]));   // sigmoid(l1 - l2)
    }
}

extern "C" void kernel_launch(void* const* d_in, const int* in_sizes, int n_in,
                              void* d_out, int out_size, void* d_ws, size_t ws_size,
                              hipStream_t stream)
{
    const int*   q1  = (const int*)  d_in[0];
    const int*   d1  = (const int*)  d_in[1];
    const int*   q2  = (const int*)  d_in[2];
    const int*   d2  = (const int*)  d_in[3];
    const float* emb = (const float*)d_in[4];
    const float* W1  = (const float*)d_in[5];
    const float* b1  = (const float*)d_in[6];
    const float* W2  = (const float*)d_in[7];
    const float* b2  = (const float*)d_in[8];
    const float* W3  = (const float*)d_in[9];
    const float* b3  = (const float*)d_in[10];
    float* out = (float*)d_out;
    (void)n_in;

    const int vocab = in_sizes[4] / 128;
    const size_t need = (size_t)vocab * 128 * 2 * 2;     // hi + lo bf16 tables

    if (ws_size >= need) {
        unsigned short* th = (unsigned short*)d_ws;
        unsigned short* tl = th + (size_t)vocab * 128;
        norm_split_kernel<<<(vocab + 7) / 8, 256, 0, stream>>>(emb, th, tl, vocab);
        knrm_kernel<true><<<out_size, 256, 0, stream>>>(q1, d1, q2, d2, emb, th, tl,
                                                        W1, b1, W2, b2, W3, b3, out);
    } else {
        knrm_kernel<false><<<out_size, 256, 0, stream>>>(q1, d1, q2, d2, emb, nullptr, nullptr,
                                                         W1, b1, W2, b2, W3, b3, out);
    }
}